// Round 1
// baseline (295.468 us; speedup 1.0000x reference)
//
#include <hip/hip_runtime.h>
#include <cstdint>
#include <cstddef>

#define Bb 8
#define Ss 2048
#define Dd 512

typedef _Float16 half8 __attribute__((ext_vector_type(8)));
typedef _Float16 half4_ __attribute__((ext_vector_type(4)));
typedef float f32x4 __attribute__((ext_vector_type(4)));

static __device__ __forceinline__ void gload_lds16(const void* g, void* l) {
  __builtin_amdgcn_global_load_lds((const __attribute__((address_space(1))) void*)g,
                                   (__attribute__((address_space(3))) void*)l,
                                   16, 0, 0);
}

// ---------------- K0a: fp32 -> fp16 bulk convert (dec) ----------------
__global__ void k0_cvt(const float* __restrict__ in, _Float16* __restrict__ out, int n8) {
  int i = blockIdx.x * blockDim.x + threadIdx.x;
  if (i >= n8) return;
  const float4* p = (const float4*)in + (size_t)i * 2;
  float4 a = p[0], b = p[1];
  half8 h;
  h[0] = (_Float16)a.x; h[1] = (_Float16)a.y; h[2] = (_Float16)a.z; h[3] = (_Float16)a.w;
  h[4] = (_Float16)b.x; h[5] = (_Float16)b.y; h[6] = (_Float16)b.z; h[7] = (_Float16)b.w;
  *(half8*)(out + (size_t)i * 8) = h;
}

// ---------------- K0b: enc fp32 -> enc16 (row-major) + encT (transposed) ----------------
__global__ void k0_enc(const float* __restrict__ enc, _Float16* __restrict__ enc16,
                       _Float16* __restrict__ encT) {
  __shared__ float tile[32][33];
  int bid = blockIdx.x;
  int b = bid & 7, kt = (bid >> 3) & 63, dt = bid >> 9;  // 8 * 64 * 16 blocks
  int key0 = kt * 32, d0 = dt * 32;
  int t = threadIdx.x;
  const float* src = enc + ((size_t)b * Ss + key0) * Dd + d0;
  _Float16* dst = enc16 + ((size_t)b * Ss + key0) * Dd + d0;
#pragma unroll
  for (int p = 0; p < 4; ++p) {
    int idx = t + p * 256;
    int r = idx >> 5, c = idx & 31;
    float v = src[(size_t)r * Dd + c];
    tile[r][c] = v;
    dst[(size_t)r * Dd + c] = (_Float16)v;
  }
  __syncthreads();
  {
    int dr = t >> 3, kq = t & 7;  // 32 d-rows x 8 key-quads
    _Float16* o = encT + ((size_t)b * Dd + d0 + dr) * Ss + key0 + kq * 4;
    half4_ v;
#pragma unroll
    for (int j = 0; j < 4; ++j) v[j] = (_Float16)tile[kq * 4 + j][dr];
    *(half4_*)o = v;
  }
}

// ---------------- K1: S = dec16 @ enc16^T  (f16 MFMA GEMM, 128x128x64 tiles) ----------------
__launch_bounds__(256, 2)
__global__ void k1_qk(const _Float16* __restrict__ A, const _Float16* __restrict__ Bm,
                      _Float16* __restrict__ S, float* __restrict__ pmax) {
  __shared__ __align__(16) _Float16 lA[128 * 64];
  __shared__ __align__(16) _Float16 lB[128 * 64];
  int bid = blockIdx.x;
  int b = bid & 7;
  int t = bid >> 3;
  int tm = t & 15, tn = t >> 4;  // 16 x 16 tiles of 128
  int tid = threadIdx.x;
  int w = tid >> 6, L = tid & 63;
  int wm = w & 1, wn = w >> 1;

  const _Float16* Ag = A + ((size_t)b * Ss + (size_t)tm * 128) * Dd;
  const _Float16* Bg = Bm + ((size_t)b * Ss + (size_t)tn * 128) * Dd;

  // per-lane staging addresses: LDS-linear slot -> swizzled global column block
  int rowS[4], colS[4], ldsOff[4];
#pragma unroll
  for (int i = 0; i < 4; ++i) {
    int se = (w * 4 + i) * 512 + L * 8;  // linear f16 slot
    int row = se >> 6;
    int blk = (se >> 3) & 7;
    rowS[i] = row;
    colS[i] = (blk ^ (row & 7)) << 3;
    ldsOff[i] = se;
  }

  f32x4 acc[4][4];
#pragma unroll
  for (int mt = 0; mt < 4; ++mt)
#pragma unroll
    for (int nt = 0; nt < 4; ++nt) acc[mt][nt] = (f32x4){0.f, 0.f, 0.f, 0.f};

  int g = L >> 4, lm = L & 15;

  for (int k0 = 0; k0 < Dd; k0 += 64) {
    __syncthreads();
#pragma unroll
    for (int i = 0; i < 4; ++i) {
      gload_lds16(Ag + (size_t)rowS[i] * Dd + k0 + colS[i], lA + ldsOff[i]);
      gload_lds16(Bg + (size_t)rowS[i] * Dd + k0 + colS[i], lB + ldsOff[i]);
    }
    __syncthreads();
#pragma unroll
    for (int ds = 0; ds < 64; ds += 32) {
      half8 af[4], bf[4];
#pragma unroll
      for (int mt = 0; mt < 4; ++mt) {
        int row = wm * 64 + mt * 16 + lm;
        int blk = ((ds >> 3) + g) ^ (row & 7);
        af[mt] = *(const half8*)(lA + row * 64 + blk * 8);
      }
#pragma unroll
      for (int nt = 0; nt < 4; ++nt) {
        int row = wn * 64 + nt * 16 + lm;
        int blk = ((ds >> 3) + g) ^ (row & 7);
        bf[nt] = *(const half8*)(lB + row * 64 + blk * 8);
      }
#pragma unroll
      for (int mt = 0; mt < 4; ++mt)
#pragma unroll
        for (int nt = 0; nt < 4; ++nt)
          acc[mt][nt] = __builtin_amdgcn_mfma_f32_16x16x32_f16(af[mt], bf[nt], acc[mt][nt], 0, 0, 0);
    }
  }

  // epilogue: write S (f16) + per-row partial max over this block's 64-col slice
  size_t rowbase = (size_t)b * Ss;
#pragma unroll
  for (int mt = 0; mt < 4; ++mt) {
#pragma unroll
    for (int r = 0; r < 4; ++r) {
      int row_g = tm * 128 + wm * 64 + mt * 16 + g * 4 + r;
      _Float16* Srow = S + (rowbase + row_g) * Ss + (size_t)tn * 128 + wn * 64 + lm;
      float rm = -1e30f;
#pragma unroll
      for (int nt = 0; nt < 4; ++nt) {
        float v = acc[mt][nt][r];
        Srow[nt * 16] = (_Float16)v;
        rm = fmaxf(rm, v);
      }
      rm = fmaxf(rm, __shfl_xor(rm, 1));
      rm = fmaxf(rm, __shfl_xor(rm, 2));
      rm = fmaxf(rm, __shfl_xor(rm, 4));
      rm = fmaxf(rm, __shfl_xor(rm, 8));
      if (lm == 0) pmax[(rowbase + row_g) * 32 + tn * 2 + wn] = rm;
    }
  }
}

// ---------------- K2: row softmax in place (S f16 -> P f16 normalized) ----------------
__global__ void k2_softmax(_Float16* __restrict__ S, const float* __restrict__ pmax) {
  int t = threadIdx.x;
  int rloc = t >> 4, sub = t & 15;  // 16 rows/block, 16 lanes/row
  size_t row = (size_t)blockIdx.x * 16 + rloc;
  const float* pm = pmax + row * 32;
  float m = -1e30f;
#pragma unroll
  for (int i = 0; i < 32; ++i) m = fmaxf(m, pm[i]);
  _Float16* Sr = S + row * Ss + (size_t)sub * 128;
  float sum = 0.f;
  for (int i = 0; i < 16; ++i) {
    half8 v = *(const half8*)(Sr + i * 8);
#pragma unroll
    for (int j = 0; j < 8; ++j) sum += __expf((float)v[j] - m);
  }
  sum += __shfl_xor(sum, 1);
  sum += __shfl_xor(sum, 2);
  sum += __shfl_xor(sum, 4);
  sum += __shfl_xor(sum, 8);
  float rinv = 1.0f / sum;
  for (int i = 0; i < 16; ++i) {
    half8 v = *(const half8*)(Sr + i * 8);
    half8 o;
#pragma unroll
    for (int j = 0; j < 8; ++j) o[j] = (_Float16)(__expf((float)v[j] - m) * rinv);
    *(half8*)(Sr + i * 8) = o;
  }
}

// ---------------- K3: C = P @ V  (A = P row-major, B-frags from encT) ----------------
__launch_bounds__(256, 2)
__global__ void k3_pv(const _Float16* __restrict__ P, const _Float16* __restrict__ Vt,
                      float* __restrict__ C) {
  __shared__ __align__(16) _Float16 lA[128 * 64];
  __shared__ __align__(16) _Float16 lB[128 * 64];
  int bid = blockIdx.x;
  int b = bid & 7;
  int t = bid >> 3;
  int tm = t & 15, tn = t >> 4;  // 16 m-tiles, 4 n-tiles
  int tid = threadIdx.x;
  int w = tid >> 6, L = tid & 63;
  int wm = w & 1, wn = w >> 1;

  const _Float16* Ag = P + ((size_t)b * Ss + (size_t)tm * 128) * Ss;   // pitch 2048
  const _Float16* Bg = Vt + ((size_t)b * Dd + (size_t)tn * 128) * Ss;  // pitch 2048

  int rowS[4], colS[4], ldsOff[4];
#pragma unroll
  for (int i = 0; i < 4; ++i) {
    int se = (w * 4 + i) * 512 + L * 8;
    int row = se >> 6;
    int blk = (se >> 3) & 7;
    rowS[i] = row;
    colS[i] = (blk ^ (row & 7)) << 3;
    ldsOff[i] = se;
  }

  f32x4 acc[4][4];
#pragma unroll
  for (int mt = 0; mt < 4; ++mt)
#pragma unroll
    for (int nt = 0; nt < 4; ++nt) acc[mt][nt] = (f32x4){0.f, 0.f, 0.f, 0.f};

  int g = L >> 4, lm = L & 15;

  for (int k0 = 0; k0 < Ss; k0 += 64) {
    __syncthreads();
#pragma unroll
    for (int i = 0; i < 4; ++i) {
      gload_lds16(Ag + (size_t)rowS[i] * Ss + k0 + colS[i], lA + ldsOff[i]);
      gload_lds16(Bg + (size_t)rowS[i] * Ss + k0 + colS[i], lB + ldsOff[i]);
    }
    __syncthreads();
#pragma unroll
    for (int ds = 0; ds < 64; ds += 32) {
      half8 af[4], bf[4];
#pragma unroll
      for (int mt = 0; mt < 4; ++mt) {
        int row = wm * 64 + mt * 16 + lm;
        int blk = ((ds >> 3) + g) ^ (row & 7);
        af[mt] = *(const half8*)(lA + row * 64 + blk * 8);
      }
#pragma unroll
      for (int nt = 0; nt < 4; ++nt) {
        int row = wn * 64 + nt * 16 + lm;
        int blk = ((ds >> 3) + g) ^ (row & 7);
        bf[nt] = *(const half8*)(lB + row * 64 + blk * 8);
      }
#pragma unroll
      for (int mt = 0; mt < 4; ++mt)
#pragma unroll
        for (int nt = 0; nt < 4; ++nt)
          acc[mt][nt] = __builtin_amdgcn_mfma_f32_16x16x32_f16(af[mt], bf[nt], acc[mt][nt], 0, 0, 0);
    }
  }

  // epilogue: fp32 store to output
#pragma unroll
  for (int mt = 0; mt < 4; ++mt) {
#pragma unroll
    for (int r = 0; r < 4; ++r) {
      int row_g = tm * 128 + wm * 64 + mt * 16 + g * 4 + r;
      float* Crow = C + ((size_t)b * Ss + row_g) * Dd + (size_t)tn * 128 + wn * 64 + lm;
#pragma unroll
      for (int nt = 0; nt < 4; ++nt) Crow[nt * 16] = acc[mt][nt][r];
    }
  }
}

extern "C" void kernel_launch(void* const* d_in, const int* in_sizes, int n_in,
                              void* d_out, int out_size, void* d_ws, size_t ws_size,
                              hipStream_t stream) {
  const float* enc = (const float*)d_in[0];  // enc_outputs [8][2048][512]
  const float* dec = (const float*)d_in[1];  // dec_outputs [8][2048][512]
  float* out = (float*)d_out;                // [8][2048][512] fp32

  const size_t nElem = (size_t)Bb * Ss * Dd;  // 8388608
  const size_t nS = (size_t)Bb * Ss * Ss;     // 33554432

  _Float16* dec16 = (_Float16*)d_ws;
  _Float16* enc16 = dec16 + nElem;
  _Float16* encT = enc16 + nElem;
  _Float16* Sp = encT + nElem;
  float* pmax = (float*)(Sp + nS);

  size_t need = nElem * 2 * 3 + nS * 2 + (size_t)Bb * Ss * 32 * 4;  // ~114 MB
  if (ws_size < need) return;  // insufficient scratch: fail validation visibly (pivot to fused flash)

  k0_cvt<<<(int)(nElem / 8 / 256), 256, 0, stream>>>(dec, dec16, (int)(nElem / 8));
  k0_enc<<<8 * 64 * 16, 256, 0, stream>>>(enc, enc16, encT);
  k1_qk<<<2048, 256, 0, stream>>>(dec16, enc16, Sp, pmax);
  k2_softmax<<<1024, 256, 0, stream>>>(Sp, pmax);
  k3_pv<<<512, 256, 0, stream>>>(Sp, encT, out);
}

// Round 2
// 209.685 us; speedup vs baseline: 1.4091x; 1.4091x over previous
//
#include <hip/hip_runtime.h>
#include <cstdint>
#include <cstddef>

#define Bb 8
#define Ss 2048
#define Dd 512

typedef _Float16 half8 __attribute__((ext_vector_type(8)));
typedef _Float16 half4_ __attribute__((ext_vector_type(4)));
typedef float f32x4 __attribute__((ext_vector_type(4)));

static __device__ __forceinline__ void gload_lds16(const void* g, void* l) {
  __builtin_amdgcn_global_load_lds((const __attribute__((address_space(1))) void*)g,
                                   (__attribute__((address_space(3))) void*)l,
                                   16, 0, 0);
}

// ---------------- K0a: fp32 -> fp16 bulk convert (dec) ----------------
__global__ void k0_cvt(const float* __restrict__ in, _Float16* __restrict__ out, int n8) {
  int i = blockIdx.x * blockDim.x + threadIdx.x;
  if (i >= n8) return;
  const float4* p = (const float4*)in + (size_t)i * 2;
  float4 a = p[0], b = p[1];
  half8 h;
  h[0] = (_Float16)a.x; h[1] = (_Float16)a.y; h[2] = (_Float16)a.z; h[3] = (_Float16)a.w;
  h[4] = (_Float16)b.x; h[5] = (_Float16)b.y; h[6] = (_Float16)b.z; h[7] = (_Float16)b.w;
  *(half8*)(out + (size_t)i * 8) = h;
}

// ---------------- K0b: enc fp32 -> enc16 (row-major) + encT (transposed) ----------------
__global__ void k0_enc(const float* __restrict__ enc, _Float16* __restrict__ enc16,
                       _Float16* __restrict__ encT) {
  __shared__ float tile[32][33];
  int bid = blockIdx.x;
  int b = bid & 7, kt = (bid >> 3) & 63, dt = bid >> 9;  // 8 * 64 * 16 blocks
  int key0 = kt * 32, d0 = dt * 32;
  int t = threadIdx.x;
  const float* src = enc + ((size_t)b * Ss + key0) * Dd + d0;
  _Float16* dst = enc16 + ((size_t)b * Ss + key0) * Dd + d0;
#pragma unroll
  for (int p = 0; p < 4; ++p) {
    int idx = t + p * 256;
    int r = idx >> 5, c = idx & 31;
    float v = src[(size_t)r * Dd + c];
    tile[r][c] = v;
    dst[(size_t)r * Dd + c] = (_Float16)v;
  }
  __syncthreads();
  {
    int dr = t >> 3, kq = t & 7;  // 32 d-rows x 8 key-quads
    _Float16* o = encT + ((size_t)b * Dd + d0 + dr) * Ss + key0 + kq * 4;
    half4_ v;
#pragma unroll
    for (int j = 0; j < 4; ++j) v[j] = (_Float16)tile[kq * 4 + j][dr];
    *(half4_*)o = v;
  }
}

// ---------------- K1: S = dec16 @ enc16^T  (f16 MFMA GEMM, 128x128x64 tiles) ----------------
__launch_bounds__(256, 2)
__global__ void k1_qk(const _Float16* __restrict__ A, const _Float16* __restrict__ Bm,
                      _Float16* __restrict__ S, float* __restrict__ pmax) {
  __shared__ __align__(16) _Float16 lA[128 * 64];
  __shared__ __align__(16) _Float16 lB[128 * 64];
  int bid = blockIdx.x;
  int b = bid & 7;
  int t = bid >> 3;
  int tm = t & 15, tn = t >> 4;  // 16 x 16 tiles of 128
  int tid = threadIdx.x;
  int w = tid >> 6, L = tid & 63;
  int wm = w & 1, wn = w >> 1;

  const _Float16* Ag = A + ((size_t)b * Ss + (size_t)tm * 128) * Dd;
  const _Float16* Bg = Bm + ((size_t)b * Ss + (size_t)tn * 128) * Dd;

  // per-lane staging addresses: LDS-linear slot -> swizzled global column block
  int rowS[4], colS[4], ldsOff[4];
#pragma unroll
  for (int i = 0; i < 4; ++i) {
    int se = (w * 4 + i) * 512 + L * 8;  // linear f16 slot
    int row = se >> 6;
    int blk = (se >> 3) & 7;
    rowS[i] = row;
    colS[i] = (blk ^ (row & 7)) << 3;
    ldsOff[i] = se;
  }

  f32x4 acc[4][4];
#pragma unroll
  for (int mt = 0; mt < 4; ++mt)
#pragma unroll
    for (int nt = 0; nt < 4; ++nt) acc[mt][nt] = (f32x4){0.f, 0.f, 0.f, 0.f};

  int g = L >> 4, lm = L & 15;

  for (int k0 = 0; k0 < Dd; k0 += 64) {
    __syncthreads();
#pragma unroll
    for (int i = 0; i < 4; ++i) {
      gload_lds16(Ag + (size_t)rowS[i] * Dd + k0 + colS[i], lA + ldsOff[i]);
      gload_lds16(Bg + (size_t)rowS[i] * Dd + k0 + colS[i], lB + ldsOff[i]);
    }
    __syncthreads();
#pragma unroll
    for (int ds = 0; ds < 64; ds += 32) {
      half8 af[4], bf[4];
#pragma unroll
      for (int mt = 0; mt < 4; ++mt) {
        int row = wm * 64 + mt * 16 + lm;
        int blk = ((ds >> 3) + g) ^ (row & 7);
        af[mt] = *(const half8*)(lA + row * 64 + blk * 8);
      }
#pragma unroll
      for (int nt = 0; nt < 4; ++nt) {
        int row = wn * 64 + nt * 16 + lm;
        int blk = ((ds >> 3) + g) ^ (row & 7);
        bf[nt] = *(const half8*)(lB + row * 64 + blk * 8);
      }
#pragma unroll
      for (int mt = 0; mt < 4; ++mt)
#pragma unroll
        for (int nt = 0; nt < 4; ++nt)
          acc[mt][nt] = __builtin_amdgcn_mfma_f32_16x16x32_f16(af[mt], bf[nt], acc[mt][nt], 0, 0, 0);
    }
  }

  // epilogue: write S (f16) + per-row partial max over this block's 64-col slice
  size_t rowbase = (size_t)b * Ss;
#pragma unroll
  for (int mt = 0; mt < 4; ++mt) {
#pragma unroll
    for (int r = 0; r < 4; ++r) {
      int row_g = tm * 128 + wm * 64 + mt * 16 + g * 4 + r;
      _Float16* Srow = S + (rowbase + row_g) * Ss + (size_t)tn * 128 + wn * 64 + lm;
      float rm = -1e30f;
#pragma unroll
      for (int nt = 0; nt < 4; ++nt) {
        float v = acc[mt][nt][r];
        Srow[nt * 16] = (_Float16)v;
        rm = fmaxf(rm, v);
      }
      rm = fmaxf(rm, __shfl_xor(rm, 1));
      rm = fmaxf(rm, __shfl_xor(rm, 2));
      rm = fmaxf(rm, __shfl_xor(rm, 4));
      rm = fmaxf(rm, __shfl_xor(rm, 8));
      if (lm == 0) pmax[(rowbase + row_g) * 32 + tn * 2 + wn] = rm;
    }
  }
}

// ---------------- K2: row softmax, wave-per-row, register-resident ----------------
// One wave owns one full 2048-elem row (4 KB). Lane L holds chunks
// {i*512 + L*8 .. +7}, i=0..3 -> every load is 64 lanes x 16 B contiguous.
// Single read + single write of S; exp computed once in fp32.
__launch_bounds__(256, 4)
__global__ void k2_softmax(_Float16* __restrict__ S, const float* __restrict__ pmax) {
  int tid = threadIdx.x;
  int w = tid >> 6, L = tid & 63;
  size_t row = (size_t)blockIdx.x * 4 + w;

  // reduce the 32 partial maxes (lanes pairwise duplicate -> broadcast reads)
  const float* pm = pmax + row * 32;
  float m = pm[L & 31];
#pragma unroll
  for (int d = 1; d <= 16; d <<= 1) m = fmaxf(m, __shfl_xor(m, d));

  _Float16* Sr = S + row * Ss;
  half8 v[4];
  float ev[4][8];
  float sum = 0.f;
#pragma unroll
  for (int i = 0; i < 4; ++i) {
    v[i] = *(const half8*)(Sr + i * 512 + L * 8);
#pragma unroll
    for (int j = 0; j < 8; ++j) {
      float e = __expf((float)v[i][j] - m);
      ev[i][j] = e;
      sum += e;
    }
  }
#pragma unroll
  for (int d = 1; d <= 32; d <<= 1) sum += __shfl_xor(sum, d);
  float rinv = 1.0f / sum;
#pragma unroll
  for (int i = 0; i < 4; ++i) {
    half8 o;
#pragma unroll
    for (int j = 0; j < 8; ++j) o[j] = (_Float16)(ev[i][j] * rinv);
    *(half8*)(Sr + i * 512 + L * 8) = o;
  }
}

// ---------------- K3: C = P @ V  (A = P row-major, B-frags from encT) ----------------
__launch_bounds__(256, 2)
__global__ void k3_pv(const _Float16* __restrict__ P, const _Float16* __restrict__ Vt,
                      float* __restrict__ C) {
  __shared__ __align__(16) _Float16 lA[128 * 64];
  __shared__ __align__(16) _Float16 lB[128 * 64];
  int bid = blockIdx.x;
  int b = bid & 7;
  int t = bid >> 3;
  int tm = t & 15, tn = t >> 4;  // 16 m-tiles, 4 n-tiles
  int tid = threadIdx.x;
  int w = tid >> 6, L = tid & 63;
  int wm = w & 1, wn = w >> 1;

  const _Float16* Ag = P + ((size_t)b * Ss + (size_t)tm * 128) * Ss;   // pitch 2048
  const _Float16* Bg = Vt + ((size_t)b * Dd + (size_t)tn * 128) * Ss;  // pitch 2048

  int rowS[4], colS[4], ldsOff[4];
#pragma unroll
  for (int i = 0; i < 4; ++i) {
    int se = (w * 4 + i) * 512 + L * 8;
    int row = se >> 6;
    int blk = (se >> 3) & 7;
    rowS[i] = row;
    colS[i] = (blk ^ (row & 7)) << 3;
    ldsOff[i] = se;
  }

  f32x4 acc[4][4];
#pragma unroll
  for (int mt = 0; mt < 4; ++mt)
#pragma unroll
    for (int nt = 0; nt < 4; ++nt) acc[mt][nt] = (f32x4){0.f, 0.f, 0.f, 0.f};

  int g = L >> 4, lm = L & 15;

  for (int k0 = 0; k0 < Ss; k0 += 64) {
    __syncthreads();
#pragma unroll
    for (int i = 0; i < 4; ++i) {
      gload_lds16(Ag + (size_t)rowS[i] * Ss + k0 + colS[i], lA + ldsOff[i]);
      gload_lds16(Bg + (size_t)rowS[i] * Ss + k0 + colS[i], lB + ldsOff[i]);
    }
    __syncthreads();
#pragma unroll
    for (int ds = 0; ds < 64; ds += 32) {
      half8 af[4], bf[4];
#pragma unroll
      for (int mt = 0; mt < 4; ++mt) {
        int row = wm * 64 + mt * 16 + lm;
        int blk = ((ds >> 3) + g) ^ (row & 7);
        af[mt] = *(const half8*)(lA + row * 64 + blk * 8);
      }
#pragma unroll
      for (int nt = 0; nt < 4; ++nt) {
        int row = wn * 64 + nt * 16 + lm;
        int blk = ((ds >> 3) + g) ^ (row & 7);
        bf[nt] = *(const half8*)(lB + row * 64 + blk * 8);
      }
#pragma unroll
      for (int mt = 0; mt < 4; ++mt)
#pragma unroll
        for (int nt = 0; nt < 4; ++nt)
          acc[mt][nt] = __builtin_amdgcn_mfma_f32_16x16x32_f16(af[mt], bf[nt], acc[mt][nt], 0, 0, 0);
    }
  }

  // epilogue: fp32 store to output
#pragma unroll
  for (int mt = 0; mt < 4; ++mt) {
#pragma unroll
    for (int r = 0; r < 4; ++r) {
      int row_g = tm * 128 + wm * 64 + mt * 16 + g * 4 + r;
      float* Crow = C + ((size_t)b * Ss + row_g) * Dd + (size_t)tn * 128 + wn * 64 + lm;
#pragma unroll
      for (int nt = 0; nt < 4; ++nt) Crow[nt * 16] = acc[mt][nt][r];
    }
  }
}

extern "C" void kernel_launch(void* const* d_in, const int* in_sizes, int n_in,
                              void* d_out, int out_size, void* d_ws, size_t ws_size,
                              hipStream_t stream) {
  const float* enc = (const float*)d_in[0];  // enc_outputs [8][2048][512]
  const float* dec = (const float*)d_in[1];  // dec_outputs [8][2048][512]
  float* out = (float*)d_out;                // [8][2048][512] fp32

  const size_t nElem = (size_t)Bb * Ss * Dd;  // 8388608
  const size_t nS = (size_t)Bb * Ss * Ss;     // 33554432

  _Float16* dec16 = (_Float16*)d_ws;
  _Float16* enc16 = dec16 + nElem;
  _Float16* encT = enc16 + nElem;
  _Float16* Sp = encT + nElem;
  float* pmax = (float*)(Sp + nS);

  size_t need = nElem * 2 * 3 + nS * 2 + (size_t)Bb * Ss * 32 * 4;  // ~114 MB
  if (ws_size < need) return;

  k0_cvt<<<(int)(nElem / 8 / 256), 256, 0, stream>>>(dec, dec16, (int)(nElem / 8));
  k0_enc<<<8 * 64 * 16, 256, 0, stream>>>(enc, enc16, encT);
  k1_qk<<<2048, 256, 0, stream>>>(dec16, enc16, Sp, pmax);
  k2_softmax<<<4096, 256, 0, stream>>>(Sp, pmax);
  k3_pv<<<512, 256, 0, stream>>>(Sp, encT, out);
}